// Round 5
// baseline (840.816 us; speedup 1.0000x reference)
//
#include <hip/hip_runtime.h>
#include <hip/hip_bf16.h>
#include <math.h>

#define T_ 128
#define NE_ 64
#define NA_ 8
#define B_ 512
#define OBS_ 64
#define D_ 128
#define CH_ 128
#define VH_ 256
#define M_ (T_*B_)   // 65536
#define TC_ 32       // GRU time-chunk
#define MC_ (TC_*B_) // 16384 rows per chunk

typedef __attribute__((ext_vector_type(8))) short bf16x8;   // 8 bf16 = 4 VGPRs
typedef __attribute__((ext_vector_type(4))) float f32x4;

__device__ __forceinline__ float sigmoidf_(float x){ return 1.f/(1.f+__expf(-x)); }

// ---------------------------------------------------------------------------
// Split-precision MFMA GEMM (fp32-accurate): C = epi(A @ B + bias)
// A given as (Ah, Al) bf16 [M][K]; B as (BTh, BTl) bf16 [N][K] (transposed).
// acc = Ah*Bh + Ah*Bl + Al*Bh  (error ~2^-16 relative — fp32-class).
// BM=128, BN=64, BK=64, 256 thr (2x2 waves, wave tile 64x32), 16x16x32 MFMA.
// WSPLIT: write hi/lo bf16 pair.  WF32: write fp32.
// ---------------------------------------------------------------------------
template<int ACT, bool WF32, bool WSPLIT>
__global__ __launch_bounds__(256)
void mgemm3_k(const __hip_bfloat16* __restrict__ Ah, const __hip_bfloat16* __restrict__ Al,
              const __hip_bfloat16* __restrict__ BTh, const __hip_bfloat16* __restrict__ BTl,
              const float* __restrict__ bias, float* __restrict__ C,
              __hip_bfloat16* __restrict__ Ch, __hip_bfloat16* __restrict__ Cl,
              int M, int N, int K)
{
  __shared__ ushort Ash[128*72], Asl[128*72];   // [m][k] stride 72
  __shared__ ushort Bsh[64*72],  Bsl[64*72];    // [n][k]
  const int tid  = threadIdx.x;
  const int lane = tid & 63, wave = tid >> 6;
  const int wm = wave >> 1, wn = wave & 1;
  const int quad = lane >> 4, ln = lane & 15;
  const int n0 = blockIdx.x * 64;
  const int m0 = blockIdx.y * 128;

  f32x4 acc[4][2];
  #pragma unroll
  for (int i=0;i<4;i++)
    #pragma unroll
    for (int j=0;j<2;j++)
      #pragma unroll
      for (int r=0;r<4;r++) acc[i][j][r] = 0.f;

  for (int kc=0; kc<K; kc+=64){
    #pragma unroll
    for (int i=0;i<4;i++){                 // A: 128 rows x 8 uint4
      int c8 = tid + i*256;
      int m = c8 >> 3, kq = (c8 & 7)*8;
      *(uint4*)&Ash[m*72+kq] = *(const uint4*)&Ah[(size_t)(m0+m)*K + kc + kq];
      *(uint4*)&Asl[m*72+kq] = *(const uint4*)&Al[(size_t)(m0+m)*K + kc + kq];
    }
    #pragma unroll
    for (int i=0;i<2;i++){                 // B: 64 rows x 8 uint4
      int c8 = tid + i*256;
      int n = c8 >> 3, kq = (c8 & 7)*8;
      *(uint4*)&Bsh[n*72+kq] = *(const uint4*)&BTh[(size_t)(n0+n)*K + kc + kq];
      *(uint4*)&Bsl[n*72+kq] = *(const uint4*)&BTl[(size_t)(n0+n)*K + kc + kq];
    }
    __syncthreads();
    #pragma unroll
    for (int ks=0; ks<2; ks++){
      const int kq = ks*32 + quad*8;
      bf16x8 ah[4], al[4], bh[2], bl[2];
      #pragma unroll
      for (int mt=0;mt<4;mt++){
        ah[mt] = *(const bf16x8*)&Ash[(wm*64 + mt*16 + ln)*72 + kq];
        al[mt] = *(const bf16x8*)&Asl[(wm*64 + mt*16 + ln)*72 + kq];
      }
      #pragma unroll
      for (int nt=0;nt<2;nt++){
        bh[nt] = *(const bf16x8*)&Bsh[(wn*32 + nt*16 + ln)*72 + kq];
        bl[nt] = *(const bf16x8*)&Bsl[(wn*32 + nt*16 + ln)*72 + kq];
      }
      #pragma unroll
      for (int mt=0;mt<4;mt++)
        #pragma unroll
        for (int nt=0;nt<2;nt++){
          acc[mt][nt] = __builtin_amdgcn_mfma_f32_16x16x32_bf16(ah[mt], bh[nt], acc[mt][nt], 0,0,0);
          acc[mt][nt] = __builtin_amdgcn_mfma_f32_16x16x32_bf16(ah[mt], bl[nt], acc[mt][nt], 0,0,0);
          acc[mt][nt] = __builtin_amdgcn_mfma_f32_16x16x32_bf16(al[mt], bh[nt], acc[mt][nt], 0,0,0);
        }
    }
    __syncthreads();
  }

  float biasv[2];
  #pragma unroll
  for (int nt=0;nt<2;nt++) biasv[nt] = bias ? bias[n0 + wn*32 + nt*16 + ln] : 0.f;
  #pragma unroll
  for (int mt=0;mt<4;mt++){
    #pragma unroll
    for (int r=0;r<4;r++){
      int row = m0 + wm*64 + mt*16 + quad*4 + r;
      #pragma unroll
      for (int nt=0;nt<2;nt++){
        int col = n0 + wn*32 + nt*16 + ln;
        float v = acc[mt][nt][r] + biasv[nt];
        if (ACT==1) v = fmaxf(v, 0.f);
        if (WF32) C[(size_t)row*N + col] = v;
        if (WSPLIT){
          __hip_bfloat16 h = __float2bfloat16(v);
          Ch[(size_t)row*N + col] = h;
          Cl[(size_t)row*N + col] = __float2bfloat16(v - __bfloat162float(h));
        }
      }
    }
  }
}

// ---------------------------------------------------------------------------
// bf16 MFMA GEMM (post-GRU path): BT = B^T [N,K] bf16; 128x128 tile, BK=128.
// ---------------------------------------------------------------------------
template<int ACT, bool DUAL, bool RESID, bool SCALE, bool WF32, bool WBF16>
__global__ __launch_bounds__(256)
void mgemm_k(const __hip_bfloat16* __restrict__ A, const __hip_bfloat16* __restrict__ A2,
             const __hip_bfloat16* __restrict__ BT, const float* __restrict__ bias,
             const float* __restrict__ resid, const int* __restrict__ dones,
             float* __restrict__ C, __hip_bfloat16* __restrict__ Cb,
             int M, int N, int K)
{
  __shared__ ushort As[128*136];
  __shared__ ushort Bs[128*136];
  const int tid  = threadIdx.x;
  const int lane = tid & 63, wave = tid >> 6;
  const int wm = wave >> 1, wn = wave & 1;
  const int quad = lane >> 4, ln = lane & 15;
  const int n0 = blockIdx.x * 128;
  const int m0 = blockIdx.y * 128;

  f32x4 acc[4][4];
  #pragma unroll
  for (int i=0;i<4;i++)
    #pragma unroll
    for (int j=0;j<4;j++)
      #pragma unroll
      for (int r=0;r<4;r++) acc[i][j][r] = 0.f;

  for (int kc=0; kc<K; kc+=128){
    const __hip_bfloat16* Ab; int arow, akoff;
    if (DUAL) { Ab = kc ? A2 : A; arow = 128; akoff = 0; }
    else      { Ab = A;           arow = K;   akoff = kc; }
    #pragma unroll
    for (int i=0;i<8;i++){
      int c8 = tid + i*256;
      int m = c8 >> 4, kq = (c8 & 15)*8;
      *(uint4*)&As[m*136 + kq] = *(const uint4*)&Ab[(size_t)(m0+m)*arow + akoff + kq];
    }
    #pragma unroll
    for (int i=0;i<8;i++){
      int c8 = tid + i*256;
      int n = c8 >> 4, kq = (c8 & 15)*8;
      *(uint4*)&Bs[n*136 + kq] = *(const uint4*)&BT[(size_t)(n0+n)*K + kc + kq];
    }
    __syncthreads();
    #pragma unroll
    for (int ks=0; ks<4; ks++){
      const int kq = ks*32 + quad*8;
      bf16x8 af[4], bfv[4];
      #pragma unroll
      for (int mt=0;mt<4;mt++)
        af[mt] = *(const bf16x8*)&As[(wm*64 + mt*16 + ln)*136 + kq];
      #pragma unroll
      for (int nt=0;nt<4;nt++)
        bfv[nt] = *(const bf16x8*)&Bs[(wn*64 + nt*16 + ln)*136 + kq];
      #pragma unroll
      for (int mt=0;mt<4;mt++)
        #pragma unroll
        for (int nt=0;nt<4;nt++)
          acc[mt][nt] = __builtin_amdgcn_mfma_f32_16x16x32_bf16(af[mt], bfv[nt], acc[mt][nt], 0,0,0);
    }
    __syncthreads();
  }

  float biasv[4];
  #pragma unroll
  for (int nt=0;nt<4;nt++){
    int col = n0 + wn*64 + nt*16 + ln;
    biasv[nt] = bias ? bias[col] : 0.f;
  }
  #pragma unroll
  for (int mt=0;mt<4;mt++){
    #pragma unroll
    for (int r=0;r<4;r++){
      int row = m0 + wm*64 + mt*16 + quad*4 + r;
      float al = 1.f;
      if (SCALE) al = (dones[row]!=0) ? 0.f : 1.f;
      #pragma unroll
      for (int nt=0;nt<4;nt++){
        int col = n0 + wn*64 + nt*16 + ln;
        float v = acc[mt][nt][r] + biasv[nt];
        if (ACT==1) v = fmaxf(v, 0.f);
        if (RESID)  v += resid[(size_t)row*N + col];
        if (SCALE)  v *= al;
        if (WF32)   C[(size_t)row*N + col] = v;
        if (WBF16)  Cb[(size_t)row*N + col] = __float2bfloat16(v);
      }
    }
  }
}

// ---------------------------------------------------------------------------
// GRU scan, weights truly in registers. 512 blocks x 384 thr, 1 row/block.
// __launch_bounds__(384,2): VGPR cap 256 so w[128] stays register-resident
// (round-4 default cap of 84 spilled it to scratch -> 75us/chunk).
// 4 independent FMA chains saturate VALU issue.
// ---------------------------------------------------------------------------
__global__ __launch_bounds__(384, 2)
void gru3_k(const float* __restrict__ gi, const float* __restrict__ hin,
            const int* __restrict__ dones, const float* __restrict__ Wh,
            const float* __restrict__ bhn, float* __restrict__ e_out,
            __hip_bfloat16* __restrict__ eb_out,
            float* __restrict__ hout, int t0, int tc)
{
  __shared__ float hs[D_];
  __shared__ float hsum[384];
  __shared__ float gis[384];
  __shared__ float dn[TC_];
  __shared__ float bhns[D_];
  const int row = blockIdx.x;
  const int c   = threadIdx.x;

  float w[D_];
  #pragma unroll
  for (int k=0;k<D_;k++) w[k] = Wh[(size_t)k*384 + c];

  for (int f=c; f<tc; f+=384)
    dn[f] = (dones[(size_t)(t0+f)*B_ + row] != 0) ? 1.f : 0.f;
  if (c < D_) { bhns[c] = bhn[c]; hs[c] = hin[(size_t)row*D_ + c]; }
  __syncthreads();
  if (c < D_ && dn[0] > 0.5f) hs[c] = 0.f;
  float gcur = gi[(size_t)row*384 + c];
  __syncthreads();

  for (int lt=0; lt<tc; lt++){
    float gn = 0.f;
    if (lt+1 < tc) gn = gi[((size_t)(lt+1)*B_ + row)*384 + c];
    float a0=0.f, a1=0.f, a2=0.f, a3=0.f;
    #pragma unroll
    for (int k=0;k<D_;k+=16){
      float4 p = *(const float4*)&hs[k];
      float4 q = *(const float4*)&hs[k+4];
      float4 s = *(const float4*)&hs[k+8];
      float4 u = *(const float4*)&hs[k+12];
      a0 = fmaf(p.x,w[k+0],a0);  a0 = fmaf(p.y,w[k+1],a0);
      a0 = fmaf(p.z,w[k+2],a0);  a0 = fmaf(p.w,w[k+3],a0);
      a1 = fmaf(q.x,w[k+4],a1);  a1 = fmaf(q.y,w[k+5],a1);
      a1 = fmaf(q.z,w[k+6],a1);  a1 = fmaf(q.w,w[k+7],a1);
      a2 = fmaf(s.x,w[k+8],a2);  a2 = fmaf(s.y,w[k+9],a2);
      a2 = fmaf(s.z,w[k+10],a2); a2 = fmaf(s.w,w[k+11],a2);
      a3 = fmaf(u.x,w[k+12],a3); a3 = fmaf(u.y,w[k+13],a3);
      a3 = fmaf(u.z,w[k+14],a3); a3 = fmaf(u.w,w[k+15],a3);
    }
    hsum[c] = (a0+a1)+(a2+a3);
    gis[c]  = gcur;
    __syncthreads();
    if (c < D_){
      float rg = sigmoidf_(gis[c]     + hsum[c]);
      float zg = sigmoidf_(gis[c+128] + hsum[c+128]);
      float x  = gis[c+256] + rg*(hsum[c+256] + bhns[c]);
      float ng = 2.f/(1.f+__expf(-2.f*x)) - 1.f;   // tanh
      float hold = hs[c];
      float hnew = (1.f - zg)*ng + zg*hold;
      float ev = hnew * (1.f - dn[lt]);
      size_t eidx = ((size_t)(t0+lt)*B_ + row)*D_ + c;
      e_out[eidx]  = ev;
      eb_out[eidx] = __float2bfloat16(ev);
      float hv = hnew;
      if (lt+1 < tc && dn[lt+1] > 0.5f) hv = 0.f;
      hs[c] = hv;
    }
    __syncthreads();
    gcur = gn;
  }
  if (c < D_) hout[(size_t)row*D_ + c] = hs[c];
}

// ---------------------------------------------------------------------------
// Coupling per (t,env): C_ij = sigmoid(relu(ai+aj+cb).w + cob), C_ii=0;
// ctx[i] = sum_j C_ij e[j]  -> bf16.
// ---------------------------------------------------------------------------
__global__ __launch_bounds__(256)
void couple_k(const float* __restrict__ acat, const float* __restrict__ e,
              const float* __restrict__ chb, const float* __restrict__ cow,
              const float* __restrict__ cob, __hip_bfloat16* __restrict__ ctxb)
{
  __shared__ float ai[NA_][CH_], aj[NA_][CH_], es[NA_][D_], cbw[CH_], cww[CH_], Cs[NA_][NA_];
  const int m0 = blockIdx.x * NA_;
  const int tid = threadIdx.x;

  for (int f = tid; f < 512; f += 256) {
    int j = f >> 6, q = (f & 63)*4;
    float4 v = *(const float4*)&acat[(size_t)(m0+j)*256 + q];
    if (q < 128) *(float4*)&ai[j][q]     = v;
    else         *(float4*)&aj[j][q-128] = v;
  }
  {
    int f = tid;
    int j = f >> 5, q = (f & 31)*4;
    *(float4*)&es[j][q] = *(const float4*)&e[(size_t)(m0+j)*D_ + q];
  }
  if (tid < 128) { cbw[tid] = chb[tid]; cww[tid] = cow[tid]; }
  __syncthreads();

  {
    int p = tid >> 2, q = tid & 3;
    int i = p >> 3, j = p & 7;
    float s = 0.f;
    #pragma unroll
    for (int h = 0; h < 32; h++){
      int hh = q*32 + h;
      s += fmaxf(ai[i][hh] + aj[j][hh] + cbw[hh], 0.f) * cww[hh];
    }
    s += __shfl_down(s, 2);
    s += __shfl_down(s, 1);
    if (q == 0) {
      float Cv = sigmoidf_(s + cob[0]);
      Cs[i][j] = (i==j) ? 0.f : Cv;
    }
  }
  __syncthreads();
  #pragma unroll
  for (int rep=0; rep<4; rep++){
    int idx = rep*256 + tid;
    int i = idx >> 7, d = idx & 127;
    float s = 0.f;
    #pragma unroll
    for (int j=0;j<NA_;j++) s = fmaf(Cs[i][j], es[j][d], s);
    ctxb[(size_t)(m0+i)*D_ + d] = __float2bfloat16(s);
  }
}

// bcatT[n][k] (256x128 bf16): B[k][n] = n<128 ? chw[k][n] : chw[128+k][n-128]
__global__ __launch_bounds__(256)
void bcatT_k(const float* __restrict__ chw, __hip_bfloat16* __restrict__ dst)
{
  int idx = blockIdx.x*256 + threadIdx.x;    // 32768
  int n = idx >> 7, k = idx & 127;
  float v = (n < 128) ? chw[k*128 + n] : chw[(128+k)*128 + (n-128)];
  dst[idx] = __float2bfloat16(v);
}

// dst[c*R + r] = bf16(src[r*C + c]);  C = 1<<Cshift
__global__ __launch_bounds__(256)
void packT_k(const float* __restrict__ src, __hip_bfloat16* __restrict__ dst,
             int R, int Cshift)
{
  int idx = blockIdx.x*256 + threadIdx.x;
  int r = idx >> Cshift, c = idx & ((1<<Cshift)-1);
  dst[c*R + r] = __float2bfloat16(src[idx]);
}

// transpose + hi/lo split: dst[(n<<Kshift)+k] = split(src[k*Ccols + n])
__global__ __launch_bounds__(256)
void packTsplit_k(const float* __restrict__ src, __hip_bfloat16* __restrict__ dh,
                  __hip_bfloat16* __restrict__ dl, int Ccols, int Kshift, int total)
{
  int idx = blockIdx.x*256 + threadIdx.x;
  if (idx >= total) return;
  int n = idx >> Kshift, k = idx & ((1<<Kshift)-1);
  float v = src[k*Ccols + n];
  __hip_bfloat16 h = __float2bfloat16(v);
  dh[idx] = h;
  dl[idx] = __float2bfloat16(v - __bfloat162float(h));
}

// elementwise hi/lo split
__global__ __launch_bounds__(256)
void split_k(const float* __restrict__ src, __hip_bfloat16* __restrict__ dh,
             __hip_bfloat16* __restrict__ dl, int n)
{
  int idx = blockIdx.x*256 + threadIdx.x;
  if (idx >= n) return;
  float v = src[idx];
  __hip_bfloat16 h = __float2bfloat16(v);
  dh[idx] = h;
  dl[idx] = __float2bfloat16(v - __bfloat162float(h));
}

// values[m] = v2[m] . w + b
__global__ __launch_bounds__(256)
void vout_k(const float* __restrict__ v2, const float* __restrict__ w,
            const float* __restrict__ b, float* __restrict__ values)
{
  int row  = blockIdx.x*4 + (threadIdx.x >> 6);
  int lane = threadIdx.x & 63;
  const float* vr = &v2[(size_t)row*VH_];
  float s = 0.f;
  #pragma unroll
  for (int i=0;i<4;i++) s = fmaf(vr[lane + 64*i], w[lane + 64*i], s);
  #pragma unroll
  for (int off=32; off; off>>=1) s += __shfl_down(s, off);
  if (lane==0) values[row] = s + b[0];
}

extern "C" void kernel_launch(void* const* d_in, const int* in_sizes, int n_in,
                              void* d_out, int out_size, void* d_ws, size_t ws_size,
                              hipStream_t stream) {
  const float* hidden = (const float*)d_in[0];
  const float* obs    = (const float*)d_in[1];
  const int*   dones  = (const int*)  d_in[2];
  const float* e1w = (const float*)d_in[3];
  const float* e1b = (const float*)d_in[4];
  const float* e2w = (const float*)d_in[5];
  const float* e2b = (const float*)d_in[6];
  const float* gWi = (const float*)d_in[7];
  const float* gbi = (const float*)d_in[8];
  const float* gWh = (const float*)d_in[9];
  const float* gbhn= (const float*)d_in[10];
  const float* chw = (const float*)d_in[11];
  const float* chb = (const float*)d_in[12];
  const float* cow = (const float*)d_in[13];
  const float* cob = (const float*)d_in[14];
  const float* uhw = (const float*)d_in[15];
  const float* uhb = (const float*)d_in[16];
  const float* uow = (const float*)d_in[17];
  const float* uob = (const float*)d_in[18];
  const float* v1w = (const float*)d_in[19];
  const float* v1b = (const float*)d_in[20];
  const float* v2w = (const float*)d_in[21];
  const float* v2b = (const float*)d_in[22];
  const float* vow = (const float*)d_in[23];
  const float* vob = (const float*)d_in[24];
  (void)in_sizes; (void)n_in; (void)out_size;

  float* out_hidden = (float*)d_out;
  float* out_values = (float*)d_out + (size_t)B_*D_;

  // Pools (float-slot offsets). Peak ~52.7M slots = 210.8 MB.
  float* ws = (float*)d_ws;
  __hip_bfloat16* emb1h = (__hip_bfloat16*)(ws);             // 4.19M slots
  __hip_bfloat16* emb1l = (__hip_bfloat16*)(ws + 4194304);   // 4.19M
  __hip_bfloat16* v1b16 = (__hip_bfloat16*)(ws);             // reuse (8.39M)
  __hip_bfloat16* obsh  = (__hip_bfloat16*)(ws + 8388608);   // 2.10M
  __hip_bfloat16* obsl  = (__hip_bfloat16*)(ws + 10485760);  // 2.10M
  __hip_bfloat16* Xc    = (__hip_bfloat16*)(ws + 8388608);   // reuse (4.19M)
  __hip_bfloat16* emb2h = (__hip_bfloat16*)(ws + 12582912);  // 4.19M
  __hip_bfloat16* emb2l = (__hip_bfloat16*)(ws + 16777216);  // 4.19M
  __hip_bfloat16* Xe    = (__hip_bfloat16*)(ws + 12582912);  // reuse emb2h (chunk-safe)
  __hip_bfloat16* Xd    = (__hip_bfloat16*)(ws + 16777216);  // reuse emb2l
  float* gi  = ws + 20971520;   // 6.29M  (chunk)
  float* P2  = ws + 27262976;   // 8.39M  e fp32
  float* P3  = ws + 35651584;   // 16.78M acat / v2 fp32
  float* Hc  = ws + 52428800;   // 65,536
  __hip_bfloat16* wb = (__hip_bfloat16*)(ws + 52494336);     // weights, ~328K bf16
  if (ws_size < (size_t)52700000 * sizeof(float)) return;

  __hip_bfloat16* bcatT = wb;             // [256][128]
  __hip_bfloat16* uhwT  = wb + 32768;     // [128][256]
  __hip_bfloat16* uowT  = wb + 65536;     // [128][128]
  __hip_bfloat16* v1wT  = wb + 81920;     // [256][128]
  __hip_bfloat16* v2wT  = wb + 114688;    // [256][256]
  __hip_bfloat16* e1wTh = wb + 180224;    // [128][64]
  __hip_bfloat16* e1wTl = wb + 188416;
  __hip_bfloat16* e2wTh = wb + 196608;    // [128][128]
  __hip_bfloat16* e2wTl = wb + 212992;
  __hip_bfloat16* gWiTh = wb + 229376;    // [384][128]
  __hip_bfloat16* gWiTl = wb + 278528;

  dim3 blk(256);
  // conversions / packs
  split_k<<<dim3(16384), blk, 0, stream>>>(obs, obsh, obsl, M_*OBS_);
  packTsplit_k<<<dim3(32),  blk, 0, stream>>>(e1w, e1wTh, e1wTl, 128, 6, 8192);
  packTsplit_k<<<dim3(64),  blk, 0, stream>>>(e2w, e2wTh, e2wTl, 128, 7, 16384);
  packTsplit_k<<<dim3(192), blk, 0, stream>>>(gWi, gWiTh, gWiTl, 384, 7, 49152);
  bcatT_k<<<dim3(128), blk, 0, stream>>>(chw, bcatT);
  packT_k<<<dim3(128), blk, 0, stream>>>(uhw, uhwT, 256, 7);
  packT_k<<<dim3(64),  blk, 0, stream>>>(uow, uowT, 128, 7);
  packT_k<<<dim3(128), blk, 0, stream>>>(v1w, v1wT, 128, 8);
  packT_k<<<dim3(256), blk, 0, stream>>>(v2w, v2wT, 256, 8);

  // embed1: relu(obs @ e1w + b) split-precision -> emb1 hi/lo
  mgemm3_k<1,false,true><<<dim3(2,512), blk, 0, stream>>>(
    obsh, obsl, e1wTh, e1wTl, e1b, nullptr, emb1h, emb1l, M_, 128, 64);
  // embed2 -> emb2 hi/lo
  mgemm3_k<1,false,true><<<dim3(2,512), blk, 0, stream>>>(
    emb1h, emb1l, e2wTh, e2wTl, e2b, nullptr, emb2h, emb2l, M_, 128, 128);

  // GRU in 4 time-chunks: gi(chunk) fp32 via split MFMA, then scan.
  for (int c4=0; c4<4; c4++){
    const __hip_bfloat16* e2hc = emb2h + (size_t)c4*MC_*D_;
    const __hip_bfloat16* e2lc = emb2l + (size_t)c4*MC_*D_;
    mgemm3_k<0,true,false><<<dim3(6,128), blk, 0, stream>>>(
      e2hc, e2lc, gWiTh, gWiTl, gbi, gi, nullptr, nullptr, MC_, 384, 128);
    const float* hin = (c4==0) ? hidden : Hc;
    float* hout = (c4==3) ? out_hidden : Hc;
    // writes Xe chunk c4 == emb2h chunk c4 region (already consumed above)
    gru3_k<<<dim3(512), dim3(384), 0, stream>>>(gi,hin,dones,gWh,gbhn,P2,Xe,hout,c4*TC_,TC_);
  }

  for (int it=0; it<2; it++){
    // acat = e @ [W1|W2] (fp32 out for couple_k)
    mgemm_k<0,false,false,false,true,false><<<dim3(2,512), blk, 0, stream>>>(
      Xe,nullptr,bcatT,nullptr,nullptr,nullptr,P3,nullptr,M_,256,128);
    couple_k<<<dim3(T_*NE_), blk, 0, stream>>>(P3, P2, chb, cow, cob, Xc);
    // dpre = relu([e|ctx] @ uhw + uhb) -> bf16
    mgemm_k<1,true,false,false,false,true><<<dim3(1,512), blk, 0, stream>>>(
      Xe,Xc,uhwT,uhb,nullptr,nullptr,nullptr,Xd,M_,128,256);
    // e = (e + relu(dpre @ uow + uob)) * alive -> fp32 (in place) + bf16
    mgemm_k<1,false,true,true,true,true><<<dim3(1,512), blk, 0, stream>>>(
      Xd,nullptr,uowT,uob,P2,dones,P2,Xe,M_,128,128);
  }
  // value head
  mgemm_k<1,false,false,false,false,true><<<dim3(2,512), blk, 0, stream>>>(
    Xe,nullptr,v1wT,v1b,nullptr,nullptr,nullptr,v1b16,M_,256,128);
  mgemm_k<1,false,false,false,true,false><<<dim3(2,512), blk, 0, stream>>>(
    v1b16,nullptr,v2wT,v2b,nullptr,nullptr,P3,nullptr,M_,256,256);
  vout_k<<<dim3(M_/4), blk, 0, stream>>>(P3, vow, vob, out_values);
}

// Round 7
// 689.042 us; speedup vs baseline: 1.2203x; 1.2203x over previous
//
#include <hip/hip_runtime.h>
#include <hip/hip_bf16.h>
#include <math.h>

#define T_ 128
#define NE_ 64
#define NA_ 8
#define B_ 512
#define OBS_ 64
#define D_ 128
#define CH_ 128
#define VH_ 256
#define M_ (T_*B_)   // 65536

typedef __attribute__((ext_vector_type(8))) short bf16x8;
typedef __attribute__((ext_vector_type(4))) float f32x4;
typedef __attribute__((ext_vector_type(4))) unsigned short u16x4;

__device__ __forceinline__ float sigmoidf_(float x){ return 1.f/(1.f+__expf(-x)); }
__device__ __forceinline__ unsigned short f2bu(float v){
  __hip_bfloat16 b = __float2bfloat16(v);
  return __builtin_bit_cast(unsigned short, b);
}
__device__ __forceinline__ float bu2f(unsigned short u){
  return __builtin_bit_cast(float, (unsigned int)u << 16);
}
__device__ __forceinline__ float ulo(unsigned int u){ return __builtin_bit_cast(float, u << 16); }
__device__ __forceinline__ float uhi(unsigned int u){ return __builtin_bit_cast(float, u & 0xFFFF0000u); }

// ---------------------------------------------------------------------------
// Split-precision MFMA GEMM (fp32-class): C = epi(A @ B + bias)
// A = (Ah,Al) bf16 [M][K]; B = (BTh,BTl) bf16 [N][K]. acc = AhBh + AhBl + AlBh.
// ---------------------------------------------------------------------------
template<int ACT, bool WF32, bool WSPLIT>
__global__ __launch_bounds__(256)
void mgemm3_k(const __hip_bfloat16* __restrict__ Ah, const __hip_bfloat16* __restrict__ Al,
              const __hip_bfloat16* __restrict__ BTh, const __hip_bfloat16* __restrict__ BTl,
              const float* __restrict__ bias, float* __restrict__ C,
              __hip_bfloat16* __restrict__ Ch, __hip_bfloat16* __restrict__ Cl,
              int M, int N, int K)
{
  __shared__ ushort Ash[128*72], Asl[128*72];
  __shared__ ushort Bsh[64*72],  Bsl[64*72];
  const int tid  = threadIdx.x;
  const int lane = tid & 63, wave = tid >> 6;
  const int wm = wave >> 1, wn = wave & 1;
  const int quad = lane >> 4, ln = lane & 15;
  const int n0 = blockIdx.x * 64;
  const int m0 = blockIdx.y * 128;

  f32x4 acc[4][2];
  #pragma unroll
  for (int i=0;i<4;i++)
    #pragma unroll
    for (int j=0;j<2;j++)
      #pragma unroll
      for (int r=0;r<4;r++) acc[i][j][r] = 0.f;

  for (int kc=0; kc<K; kc+=64){
    #pragma unroll
    for (int i=0;i<4;i++){
      int c8 = tid + i*256;
      int m = c8 >> 3, kq = (c8 & 7)*8;
      *(uint4*)&Ash[m*72+kq] = *(const uint4*)&Ah[(size_t)(m0+m)*K + kc + kq];
      *(uint4*)&Asl[m*72+kq] = *(const uint4*)&Al[(size_t)(m0+m)*K + kc + kq];
    }
    #pragma unroll
    for (int i=0;i<2;i++){
      int c8 = tid + i*256;
      int n = c8 >> 3, kq = (c8 & 7)*8;
      *(uint4*)&Bsh[n*72+kq] = *(const uint4*)&BTh[(size_t)(n0+n)*K + kc + kq];
      *(uint4*)&Bsl[n*72+kq] = *(const uint4*)&BTl[(size_t)(n0+n)*K + kc + kq];
    }
    __syncthreads();
    #pragma unroll
    for (int ks=0; ks<2; ks++){
      const int kq = ks*32 + quad*8;
      bf16x8 ah[4], al[4], bh[2], bl[2];
      #pragma unroll
      for (int mt=0;mt<4;mt++){
        ah[mt] = *(const bf16x8*)&Ash[(wm*64 + mt*16 + ln)*72 + kq];
        al[mt] = *(const bf16x8*)&Asl[(wm*64 + mt*16 + ln)*72 + kq];
      }
      #pragma unroll
      for (int nt=0;nt<2;nt++){
        bh[nt] = *(const bf16x8*)&Bsh[(wn*32 + nt*16 + ln)*72 + kq];
        bl[nt] = *(const bf16x8*)&Bsl[(wn*32 + nt*16 + ln)*72 + kq];
      }
      #pragma unroll
      for (int mt=0;mt<4;mt++)
        #pragma unroll
        for (int nt=0;nt<2;nt++){
          acc[mt][nt] = __builtin_amdgcn_mfma_f32_16x16x32_bf16(ah[mt], bh[nt], acc[mt][nt], 0,0,0);
          acc[mt][nt] = __builtin_amdgcn_mfma_f32_16x16x32_bf16(ah[mt], bl[nt], acc[mt][nt], 0,0,0);
          acc[mt][nt] = __builtin_amdgcn_mfma_f32_16x16x32_bf16(al[mt], bh[nt], acc[mt][nt], 0,0,0);
        }
    }
    __syncthreads();
  }

  float biasv[2];
  #pragma unroll
  for (int nt=0;nt<2;nt++) biasv[nt] = bias ? bias[n0 + wn*32 + nt*16 + ln] : 0.f;
  #pragma unroll
  for (int mt=0;mt<4;mt++){
    #pragma unroll
    for (int r=0;r<4;r++){
      int row = m0 + wm*64 + mt*16 + quad*4 + r;
      #pragma unroll
      for (int nt=0;nt<2;nt++){
        int col = n0 + wn*32 + nt*16 + ln;
        float v = acc[mt][nt][r] + biasv[nt];
        if (ACT==1) v = fmaxf(v, 0.f);
        if (WF32) C[(size_t)row*N + col] = v;
        if (WSPLIT){
          __hip_bfloat16 h = __float2bfloat16(v);
          Ch[(size_t)row*N + col] = h;
          Cl[(size_t)row*N + col] = __float2bfloat16(v - __bfloat162float(h));
        }
      }
    }
  }
}

// ---------------------------------------------------------------------------
// bf16 MFMA GEMM (post-GRU): BT = B^T [N,K] bf16; 128x128 tile, BK=128.
// RESID: += bf16 resid AFTER act.  SCALE: *= alive.  Write bf16.
// ---------------------------------------------------------------------------
template<int ACT, bool DUAL, bool RESID, bool SCALE>
__global__ __launch_bounds__(256)
void mgemm_k(const __hip_bfloat16* __restrict__ A, const __hip_bfloat16* __restrict__ A2,
             const __hip_bfloat16* __restrict__ BT, const float* __restrict__ bias,
             const unsigned short* __restrict__ resid, const int* __restrict__ dones,
             __hip_bfloat16* __restrict__ Cb, int M, int N, int K)
{
  __shared__ ushort As[128*136];
  __shared__ ushort Bs[128*136];
  const int tid  = threadIdx.x;
  const int lane = tid & 63, wave = tid >> 6;
  const int wm = wave >> 1, wn = wave & 1;
  const int quad = lane >> 4, ln = lane & 15;
  const int n0 = blockIdx.x * 128;
  const int m0 = blockIdx.y * 128;

  f32x4 acc[4][4];
  #pragma unroll
  for (int i=0;i<4;i++)
    #pragma unroll
    for (int j=0;j<4;j++)
      #pragma unroll
      for (int r=0;r<4;r++) acc[i][j][r] = 0.f;

  for (int kc=0; kc<K; kc+=128){
    const __hip_bfloat16* Ab; int arow, akoff;
    if (DUAL) { Ab = kc ? A2 : A; arow = 128; akoff = 0; }
    else      { Ab = A;           arow = K;   akoff = kc; }
    #pragma unroll
    for (int i=0;i<8;i++){
      int c8 = tid + i*256;
      int m = c8 >> 4, kq = (c8 & 15)*8;
      *(uint4*)&As[m*136 + kq] = *(const uint4*)&Ab[(size_t)(m0+m)*arow + akoff + kq];
    }
    #pragma unroll
    for (int i=0;i<8;i++){
      int c8 = tid + i*256;
      int n = c8 >> 4, kq = (c8 & 15)*8;
      *(uint4*)&Bs[n*136 + kq] = *(const uint4*)&BT[(size_t)(n0+n)*K + kc + kq];
    }
    __syncthreads();
    #pragma unroll
    for (int ks=0; ks<4; ks++){
      const int kq = ks*32 + quad*8;
      bf16x8 af[4], bfv[4];
      #pragma unroll
      for (int mt=0;mt<4;mt++)
        af[mt] = *(const bf16x8*)&As[(wm*64 + mt*16 + ln)*136 + kq];
      #pragma unroll
      for (int nt=0;nt<4;nt++)
        bfv[nt] = *(const bf16x8*)&Bs[(wn*64 + nt*16 + ln)*136 + kq];
      #pragma unroll
      for (int mt=0;mt<4;mt++)
        #pragma unroll
        for (int nt=0;nt<4;nt++)
          acc[mt][nt] = __builtin_amdgcn_mfma_f32_16x16x32_bf16(af[mt], bfv[nt], acc[mt][nt], 0,0,0);
    }
    __syncthreads();
  }

  float biasv[4];
  #pragma unroll
  for (int nt=0;nt<4;nt++){
    int col = n0 + wn*64 + nt*16 + ln;
    biasv[nt] = bias ? bias[col] : 0.f;
  }
  #pragma unroll
  for (int mt=0;mt<4;mt++){
    #pragma unroll
    for (int r=0;r<4;r++){
      int row = m0 + wm*64 + mt*16 + quad*4 + r;
      float al = 1.f;
      if (SCALE) al = (dones[row]!=0) ? 0.f : 1.f;
      #pragma unroll
      for (int nt=0;nt<4;nt++){
        int col = n0 + wn*64 + nt*16 + ln;
        float v = acc[mt][nt][r] + biasv[nt];
        if (ACT==1) v = fmaxf(v, 0.f);
        if (RESID)  v += bu2f(resid[(size_t)row*N + col]);
        if (SCALE)  v *= al;
        Cb[(size_t)row*N + col] = __float2bfloat16(v);
      }
    }
  }
}

// ---------------------------------------------------------------------------
// MFMA GRU, one dispatch for the whole T=128 scan.
// 32 blocks x 512 thr (8 waves). Block owns 16 rows; wave owns 48 gate-cols.
// Wh hi AND lo B-fragments in registers (96 VGPR), staged via LDS.
// gh = h_hi@Wh_hi + h_lo@Wh_hi + h_hi@Wh_lo  (fp32-class, ~1e-5).
// FIX vs round 6: carry register takes the RESET h (hcur = hv) so the z-gate
// leak term is zg*0 on done rows — round 6 leaked the unreset h (8.8e-2 err).
// Final step has dnext=0, so hout still receives the unreset final h.
// ---------------------------------------------------------------------------
__global__ __launch_bounds__(512, 1)
void grum_k(const float* __restrict__ giA, const float* __restrict__ giB,
            const float* __restrict__ hidden0,
            const int* __restrict__ dones, const float* __restrict__ gWh,
            const float* __restrict__ bhn, __hip_bfloat16* __restrict__ eb_out,
            float* __restrict__ hout)
{
  __shared__ float ghs[384*20];          // [gatecol][hrow(16)+pad4] / weight staging
  __shared__ ushort hhi[16*136], hlo[16*136];
  __shared__ float dnS[T_*16];           // [t][row]
  __shared__ float bhnS[D_];
  const int tid  = threadIdx.x;
  const int lane = tid & 63, wave = tid >> 6;   // 8 waves
  const int quad = lane >> 4, ln = lane & 15;
  const int r0   = blockIdx.x * 16;
  const int grow = tid & 15, gcb = (tid >> 4) * 4;   // gate-thread: row, 4 h-cols

  for (int i = tid; i < T_*16; i += 512)
    dnS[i] = (dones[(size_t)(i>>4)*B_ + r0 + (i&15)] != 0) ? 1.f : 0.f;
  if (tid < D_) bhnS[tid] = bhn[tid];

  // Wh -> hi and lo B-fragments in registers, staged through LDS
  bf16x8 bfh[3][4], bfl[3][4];
  ushort* wstg = (ushort*)ghs;   // 32 x 392 ushorts = 25KB
  #pragma unroll
  for (int kc=0; kc<4; kc++){    // hi pass
    for (int i = tid; i < 32*384; i += 512){
      int kk = i / 384, col = i - kk*384;
      wstg[kk*392 + col] = f2bu(gWh[(size_t)(kc*32 + kk)*384 + col]);
    }
    __syncthreads();
    #pragma unroll
    for (int ct=0; ct<3; ct++){
      int col = wave*48 + ct*16 + ln;
      #pragma unroll
      for (int j=0;j<8;j++)
        bfh[ct][kc][j] = (short)wstg[(quad*8+j)*392 + col];
    }
    __syncthreads();
  }
  #pragma unroll
  for (int kc=0; kc<4; kc++){    // lo pass
    for (int i = tid; i < 32*384; i += 512){
      int kk = i / 384, col = i - kk*384;
      float v = gWh[(size_t)(kc*32 + kk)*384 + col];
      wstg[kk*392 + col] = f2bu(v - bu2f(f2bu(v)));
    }
    __syncthreads();
    #pragma unroll
    for (int ct=0; ct<3; ct++){
      int col = wave*48 + ct*16 + ln;
      #pragma unroll
      for (int j=0;j<8;j++)
        bfl[ct][kc][j] = (short)wstg[(quad*8+j)*392 + col];
    }
    __syncthreads();
  }

  // init h (apply dones[0])
  f32x4 hcur = *(const f32x4*)&hidden0[(size_t)(r0+grow)*D_ + gcb];
  if (dnS[grow] > 0.5f) { hcur[0]=0.f; hcur[1]=0.f; hcur[2]=0.f; hcur[3]=0.f; }
  {
    u16x4 hh, hl;
    #pragma unroll
    for (int i=0;i<4;i++){ hh[i]=f2bu(hcur[i]); hl[i]=f2bu(hcur[i]-bu2f(hh[i])); }
    *(u16x4*)&hhi[grow*136 + gcb] = hh;
    *(u16x4*)&hlo[grow*136 + gcb] = hl;
  }
  __syncthreads();

  for (int t=0; t<T_; t++){
    const float* gp = (t < 64) ? giA + ((size_t)t*B_ + r0 + grow)*384
                               : giB + ((size_t)(t-64)*B_ + r0 + grow)*384;
    f32x4 gr  = *(const f32x4*)&gp[gcb];
    f32x4 gz  = *(const f32x4*)&gp[gcb + 128];
    f32x4 gn4 = *(const f32x4*)&gp[gcb + 256];

    // gh = h_hi@Wh_hi + h_lo@Wh_hi + h_hi@Wh_lo
    f32x4 acc[3];
    #pragma unroll
    for (int ct=0;ct<3;ct++)
      #pragma unroll
      for (int r=0;r<4;r++) acc[ct][r]=0.f;
    #pragma unroll
    for (int ks=0; ks<4; ks++){
      bf16x8 ahi = *(const bf16x8*)&hhi[ln*136 + ks*32 + quad*8];
      bf16x8 alo = *(const bf16x8*)&hlo[ln*136 + ks*32 + quad*8];
      #pragma unroll
      for (int ct=0;ct<3;ct++){
        acc[ct] = __builtin_amdgcn_mfma_f32_16x16x32_bf16(ahi, bfh[ct][ks], acc[ct], 0,0,0);
        acc[ct] = __builtin_amdgcn_mfma_f32_16x16x32_bf16(alo, bfh[ct][ks], acc[ct], 0,0,0);
        acc[ct] = __builtin_amdgcn_mfma_f32_16x16x32_bf16(ahi, bfl[ct][ks], acc[ct], 0,0,0);
      }
    }
    #pragma unroll
    for (int ct=0;ct<3;ct++)
      *(f32x4*)&ghs[(wave*48 + ct*16 + ln)*20 + quad*4] = acc[ct];
    __syncthreads();

    const float dnow = dnS[t*16 + grow];
    const float dnext = (t+1 < T_) ? dnS[(t+1)*16 + grow] : 0.f;
    u16x4 eu, hh, hl;
    #pragma unroll
    for (int i=0;i<4;i++){
      int col = gcb + i;
      float rg = sigmoidf_(gr[i]  + ghs[col*20 + grow]);
      float zg = sigmoidf_(gz[i]  + ghs[(col+128)*20 + grow]);
      float x  = gn4[i] + rg*(ghs[(col+256)*20 + grow] + bhnS[col]);
      float ng = 2.f/(1.f+__expf(-2.f*x)) - 1.f;
      float hnew = (1.f - zg)*ng + zg*hcur[i];
      eu[i] = f2bu(hnew * (1.f - dnow));
      float hv = (dnext > 0.5f) ? 0.f : hnew;
      hcur[i] = hv;                         // FIX: carry the RESET h
      hh[i] = f2bu(hv); hl[i] = f2bu(hv - bu2f(hh[i]));
    }
    *(u16x4*)&eb_out[((size_t)t*B_ + r0 + grow)*D_ + gcb] = *(u16x4*)&eu;
    *(u16x4*)&hhi[grow*136 + gcb] = hh;
    *(u16x4*)&hlo[grow*136 + gcb] = hl;
    __syncthreads();
  }
  *(f32x4*)&hout[(size_t)(r0+grow)*D_ + gcb] = hcur;
}

// ---------------------------------------------------------------------------
// Coupling per (t,env), bf16 inputs: C_ij = sigmoid(relu(ai+aj+cb).w + cob),
// C_ii=0; ctx[i] = sum_j C_ij e[j] -> bf16.
// ---------------------------------------------------------------------------
__global__ __launch_bounds__(256)
void couple_k(const __hip_bfloat16* __restrict__ acat, const __hip_bfloat16* __restrict__ e,
              const float* __restrict__ chb, const float* __restrict__ cow,
              const float* __restrict__ cob, __hip_bfloat16* __restrict__ ctxb)
{
  __shared__ float ai[NA_][CH_], aj[NA_][CH_], es[NA_][D_], cbw[CH_], cww[CH_], Cs[NA_][NA_];
  const int m0 = blockIdx.x * NA_;
  const int tid = threadIdx.x;

  {
    int j = tid >> 5, q = (tid & 31)*8;
    uint4 u = *(const uint4*)((const ushort*)acat + (size_t)(m0+j)*256 + q);
    float f[8] = {ulo(u.x),uhi(u.x),ulo(u.y),uhi(u.y),ulo(u.z),uhi(u.z),ulo(u.w),uhi(u.w)};
    float* dst = (q < 128) ? &ai[j][q] : &aj[j][q-128];
    #pragma unroll
    for (int i=0;i<8;i++) dst[i] = f[i];
  }
  if (tid < 128){
    int j = tid >> 4, q = (tid & 15)*8;
    uint4 u = *(const uint4*)((const ushort*)e + (size_t)(m0+j)*D_ + q);
    float f[8] = {ulo(u.x),uhi(u.x),ulo(u.y),uhi(u.y),ulo(u.z),uhi(u.z),ulo(u.w),uhi(u.w)};
    #pragma unroll
    for (int i=0;i<8;i++) es[j][q+i] = f[i];
    cbw[tid] = chb[tid]; cww[tid] = cow[tid];
  }
  __syncthreads();

  {
    int p = tid >> 2, q = tid & 3;
    int i = p >> 3, j = p & 7;
    float s = 0.f;
    #pragma unroll
    for (int h = 0; h < 32; h++){
      int hh = q*32 + h;
      s += fmaxf(ai[i][hh] + aj[j][hh] + cbw[hh], 0.f) * cww[hh];
    }
    s += __shfl_down(s, 2);
    s += __shfl_down(s, 1);
    if (q == 0) {
      float Cv = sigmoidf_(s + cob[0]);
      Cs[i][j] = (i==j) ? 0.f : Cv;
    }
  }
  __syncthreads();
  #pragma unroll
  for (int rep=0; rep<4; rep++){
    int idx = rep*256 + tid;
    int i = idx >> 7, d = idx & 127;
    float s = 0.f;
    #pragma unroll
    for (int j=0;j<NA_;j++) s = fmaf(Cs[i][j], es[j][d], s);
    ctxb[(size_t)(m0+i)*D_ + d] = __float2bfloat16(s);
  }
}

__global__ __launch_bounds__(256)
void bcatT_k(const float* __restrict__ chw, __hip_bfloat16* __restrict__ dst)
{
  int idx = blockIdx.x*256 + threadIdx.x;
  int n = idx >> 7, k = idx & 127;
  float v = (n < 128) ? chw[k*128 + n] : chw[(128+k)*128 + (n-128)];
  dst[idx] = __float2bfloat16(v);
}

__global__ __launch_bounds__(256)
void packT_k(const float* __restrict__ src, __hip_bfloat16* __restrict__ dst,
             int R, int Cshift)
{
  int idx = blockIdx.x*256 + threadIdx.x;
  int r = idx >> Cshift, c = idx & ((1<<Cshift)-1);
  dst[c*R + r] = __float2bfloat16(src[idx]);
}

__global__ __launch_bounds__(256)
void packTsplit_k(const float* __restrict__ src, __hip_bfloat16* __restrict__ dh,
                  __hip_bfloat16* __restrict__ dl, int Ccols, int Kshift, int total)
{
  int idx = blockIdx.x*256 + threadIdx.x;
  if (idx >= total) return;
  int n = idx >> Kshift, k = idx & ((1<<Kshift)-1);
  float v = src[k*Ccols + n];
  __hip_bfloat16 h = __float2bfloat16(v);
  dh[idx] = h;
  dl[idx] = __float2bfloat16(v - __bfloat162float(h));
}

__global__ __launch_bounds__(256)
void split_k(const float* __restrict__ src, __hip_bfloat16* __restrict__ dh,
             __hip_bfloat16* __restrict__ dl, int n)
{
  int idx = blockIdx.x*256 + threadIdx.x;
  if (idx >= n) return;
  float v = src[idx];
  __hip_bfloat16 h = __float2bfloat16(v);
  dh[idx] = h;
  dl[idx] = __float2bfloat16(v - __bfloat162float(h));
}

__global__ __launch_bounds__(256)
void vout_k(const __hip_bfloat16* __restrict__ v2, const float* __restrict__ w,
            const float* __restrict__ b, float* __restrict__ values)
{
  int row  = blockIdx.x*4 + (threadIdx.x >> 6);
  int lane = threadIdx.x & 63;
  const ushort* vr = (const ushort*)v2 + (size_t)row*VH_;
  float s = 0.f;
  #pragma unroll
  for (int i=0;i<4;i++) s = fmaf(bu2f(vr[lane + 64*i]), w[lane + 64*i], s);
  #pragma unroll
  for (int off=32; off; off>>=1) s += __shfl_down(s, off);
  if (lane==0) values[row] = s + b[0];
}

extern "C" void kernel_launch(void* const* d_in, const int* in_sizes, int n_in,
                              void* d_out, int out_size, void* d_ws, size_t ws_size,
                              hipStream_t stream) {
  const float* hidden = (const float*)d_in[0];
  const float* obs    = (const float*)d_in[1];
  const int*   dones  = (const int*)  d_in[2];
  const float* e1w = (const float*)d_in[3];
  const float* e1b = (const float*)d_in[4];
  const float* e2w = (const float*)d_in[5];
  const float* e2b = (const float*)d_in[6];
  const float* gWi = (const float*)d_in[7];
  const float* gbi = (const float*)d_in[8];
  const float* gWh = (const float*)d_in[9];
  const float* gbhn= (const float*)d_in[10];
  const float* chw = (const float*)d_in[11];
  const float* chb = (const float*)d_in[12];
  const float* cow = (const float*)d_in[13];
  const float* cob = (const float*)d_in[14];
  const float* uhw = (const float*)d_in[15];
  const float* uhb = (const float*)d_in[16];
  const float* uow = (const float*)d_in[17];
  const float* uob = (const float*)d_in[18];
  const float* v1w = (const float*)d_in[19];
  const float* v1b = (const float*)d_in[20];
  const float* v2w = (const float*)d_in[21];
  const float* v2b = (const float*)d_in[22];
  const float* vow = (const float*)d_in[23];
  const float* vob = (const float*)d_in[24];
  (void)in_sizes; (void)n_in; (void)out_size;

  float* out_hidden = (float*)d_out;
  float* out_values = (float*)d_out + (size_t)B_*D_;

  // Arena (float-slot offsets). Peak 38.1M slots = 152 MB (ws >= 218 MB known).
  float* ws = (float*)d_ws;
  __hip_bfloat16* obsh  = (__hip_bfloat16*)(ws);             // [0, 2.10M)
  __hip_bfloat16* obsl  = (__hip_bfloat16*)(ws + 2097152);   // [2.10M, 4.19M)
  __hip_bfloat16* emb1h = (__hip_bfloat16*)(ws + 4194304);   // [4.19M, 8.39M)
  __hip_bfloat16* emb1l = (__hip_bfloat16*)(ws + 8388608);   // [8.39M, 12.58M)
  __hip_bfloat16* emb2h = (__hip_bfloat16*)(ws + 12582912);  // [12.58M, 16.78M)
  __hip_bfloat16* emb2l = (__hip_bfloat16*)(ws + 16777216);  // [16.78M, 20.97M)
  float* giA = ws;                                            // [0, 12.58M)  overlays obs+emb1
  float* giB = ws + 20971520;                                 // [20.97M, 33.55M)
  __hip_bfloat16* Xe    = (__hip_bfloat16*)(ws + 33554432);   // [33.55M, 37.75M) e bf16
  __hip_bfloat16* wb    = (__hip_bfloat16*)(ws + 37748736);   // weights (~332K slots-as-bf16)
  // post-GRU overlays (gi / emb regions dead):
  __hip_bfloat16* acatB = (__hip_bfloat16*)(ws);              // [0, 8.39M)
  __hip_bfloat16* Xc    = (__hip_bfloat16*)(ws + 8388608);    // [8.39M, 12.58M)
  __hip_bfloat16* Xd    = (__hip_bfloat16*)(ws + 12582912);   // [12.58M, 16.78M)
  __hip_bfloat16* v1b16 = (__hip_bfloat16*)(ws + 20971520);   // [20.97M, 29.36M)
  __hip_bfloat16* v2b16 = (__hip_bfloat16*)(ws);              // [0, 8.39M)  (acat dead)
  if (ws_size < (size_t)38100000 * sizeof(float)) return;

  __hip_bfloat16* bcatT = wb;             // [256][128]
  __hip_bfloat16* uhwT  = wb + 32768;     // [128][256]
  __hip_bfloat16* uowT  = wb + 65536;     // [128][128]
  __hip_bfloat16* v1wT  = wb + 81920;     // [256][128]
  __hip_bfloat16* v2wT  = wb + 114688;    // [256][256]
  __hip_bfloat16* e1wTh = wb + 180224;    // [128][64]
  __hip_bfloat16* e1wTl = wb + 188416;
  __hip_bfloat16* e2wTh = wb + 196608;    // [128][128]
  __hip_bfloat16* e2wTl = wb + 212992;
  __hip_bfloat16* gWiTh = wb + 229376;    // [384][128]
  __hip_bfloat16* gWiTl = wb + 278528;

  dim3 blk(256);
  split_k<<<dim3(16384), blk, 0, stream>>>(obs, obsh, obsl, M_*OBS_);
  packTsplit_k<<<dim3(32),  blk, 0, stream>>>(e1w, e1wTh, e1wTl, 128, 6, 8192);
  packTsplit_k<<<dim3(64),  blk, 0, stream>>>(e2w, e2wTh, e2wTl, 128, 7, 16384);
  packTsplit_k<<<dim3(192), blk, 0, stream>>>(gWi, gWiTh, gWiTl, 384, 7, 49152);
  bcatT_k<<<dim3(128), blk, 0, stream>>>(chw, bcatT);
  packT_k<<<dim3(128), blk, 0, stream>>>(uhw, uhwT, 256, 7);
  packT_k<<<dim3(64),  blk, 0, stream>>>(uow, uowT, 128, 7);
  packT_k<<<dim3(128), blk, 0, stream>>>(v1w, v1wT, 128, 8);
  packT_k<<<dim3(256), blk, 0, stream>>>(v2w, v2wT, 256, 8);

  // embeds (split-precision, fp32-class)
  mgemm3_k<1,false,true><<<dim3(2,512), blk, 0, stream>>>(
    obsh, obsl, e1wTh, e1wTl, e1b, nullptr, emb1h, emb1l, M_, 128, 64);
  mgemm3_k<1,false,true><<<dim3(2,512), blk, 0, stream>>>(
    emb1h, emb1l, e2wTh, e2wTl, e2b, nullptr, emb2h, emb2l, M_, 128, 128);
  // gi in two halves (fp32 out): t=0..63 -> giA (overlays dead obs/emb1), t=64..127 -> giB
  mgemm3_k<0,true,false><<<dim3(6,256), blk, 0, stream>>>(
    emb2h, emb2l, gWiTh, gWiTl, gbi, giA, nullptr, nullptr, M_/2, 384, 128);
  mgemm3_k<0,true,false><<<dim3(6,256), blk, 0, stream>>>(
    emb2h + (size_t)(M_/2)*D_, emb2l + (size_t)(M_/2)*D_, gWiTh, gWiTl, gbi, giB,
    nullptr, nullptr, M_/2, 384, 128);

  // MFMA GRU: one dispatch, whole scan
  grum_k<<<dim3(32), dim3(512), 0, stream>>>(giA, giB, hidden, dones, gWh, gbhn, Xe, out_hidden);

  for (int it=0; it<2; it++){
    mgemm_k<0,false,false,false><<<dim3(2,512), blk, 0, stream>>>(
      Xe, nullptr, bcatT, nullptr, nullptr, nullptr, acatB, M_, 256, 128);
    couple_k<<<dim3(T_*NE_), blk, 0, stream>>>(acatB, Xe, chb, cow, cob, Xc);
    mgemm_k<1,true,false,false><<<dim3(1,512), blk, 0, stream>>>(
      Xe, Xc, uhwT, uhb, nullptr, nullptr, Xd, M_, 128, 256);
    mgemm_k<1,false,true,true><<<dim3(1,512), blk, 0, stream>>>(
      Xd, nullptr, uowT, uob, (const unsigned short*)Xe, dones, Xe, M_, 128, 128);
  }
  mgemm_k<1,false,false,false><<<dim3(2,512), blk, 0, stream>>>(
    Xe, nullptr, v1wT, v1b, nullptr, nullptr, v1b16, M_, 256, 128);
  mgemm_k<1,false,false,false><<<dim3(2,512), blk, 0, stream>>>(
    v1b16, nullptr, v2wT, v2b, nullptr, nullptr, v2b16, M_, 256, 256);
  vout_k<<<dim3(M_/4), blk, 0, stream>>>(v2b16, vow, vob, out_values);
}

// Round 8
// 589.141 us; speedup vs baseline: 1.4272x; 1.1696x over previous
//
#include <hip/hip_runtime.h>
#include <hip/hip_bf16.h>
#include <math.h>

#define T_ 128
#define NE_ 64
#define NA_ 8
#define B_ 512
#define OBS_ 64
#define D_ 128
#define CH_ 128
#define VH_ 256
#define M_ (T_*B_)   // 65536

typedef __attribute__((ext_vector_type(8))) short bf16x8;
typedef __attribute__((ext_vector_type(4))) float f32x4;
typedef __attribute__((ext_vector_type(4))) unsigned short u16x4;

__device__ __forceinline__ float sigmoidf_(float x){ return 1.f/(1.f+__expf(-x)); }
__device__ __forceinline__ unsigned short f2bu(float v){
  __hip_bfloat16 b = __float2bfloat16(v);
  return __builtin_bit_cast(unsigned short, b);
}
__device__ __forceinline__ float bu2f(unsigned short u){
  return __builtin_bit_cast(float, (unsigned int)u << 16);
}
__device__ __forceinline__ float ulo(unsigned int u){ return __builtin_bit_cast(float, u << 16); }
__device__ __forceinline__ float uhi(unsigned int u){ return __builtin_bit_cast(float, u & 0xFFFF0000u); }

// ---------------------------------------------------------------------------
// Split-precision MFMA GEMM (fp32-class): C = epi(A @ B + bias)
// A = (Ah,Al) bf16 [M][K]; B = (BTh,BTl) bf16 [N][K]. acc = AhBh + AhBl + AlBh.
// ---------------------------------------------------------------------------
template<int ACT, bool WF32, bool WSPLIT>
__global__ __launch_bounds__(256)
void mgemm3_k(const __hip_bfloat16* __restrict__ Ah, const __hip_bfloat16* __restrict__ Al,
              const __hip_bfloat16* __restrict__ BTh, const __hip_bfloat16* __restrict__ BTl,
              const float* __restrict__ bias, float* __restrict__ C,
              __hip_bfloat16* __restrict__ Ch, __hip_bfloat16* __restrict__ Cl,
              int M, int N, int K)
{
  __shared__ ushort Ash[128*72], Asl[128*72];
  __shared__ ushort Bsh[64*72],  Bsl[64*72];
  const int tid  = threadIdx.x;
  const int lane = tid & 63, wave = tid >> 6;
  const int wm = wave >> 1, wn = wave & 1;
  const int quad = lane >> 4, ln = lane & 15;
  const int n0 = blockIdx.x * 64;
  const int m0 = blockIdx.y * 128;

  f32x4 acc[4][2];
  #pragma unroll
  for (int i=0;i<4;i++)
    #pragma unroll
    for (int j=0;j<2;j++)
      #pragma unroll
      for (int r=0;r<4;r++) acc[i][j][r] = 0.f;

  for (int kc=0; kc<K; kc+=64){
    #pragma unroll
    for (int i=0;i<4;i++){
      int c8 = tid + i*256;
      int m = c8 >> 3, kq = (c8 & 7)*8;
      *(uint4*)&Ash[m*72+kq] = *(const uint4*)&Ah[(size_t)(m0+m)*K + kc + kq];
      *(uint4*)&Asl[m*72+kq] = *(const uint4*)&Al[(size_t)(m0+m)*K + kc + kq];
    }
    #pragma unroll
    for (int i=0;i<2;i++){
      int c8 = tid + i*256;
      int n = c8 >> 3, kq = (c8 & 7)*8;
      *(uint4*)&Bsh[n*72+kq] = *(const uint4*)&BTh[(size_t)(n0+n)*K + kc + kq];
      *(uint4*)&Bsl[n*72+kq] = *(const uint4*)&BTl[(size_t)(n0+n)*K + kc + kq];
    }
    __syncthreads();
    #pragma unroll
    for (int ks=0; ks<2; ks++){
      const int kq = ks*32 + quad*8;
      bf16x8 ah[4], al[4], bh[2], bl[2];
      #pragma unroll
      for (int mt=0;mt<4;mt++){
        ah[mt] = *(const bf16x8*)&Ash[(wm*64 + mt*16 + ln)*72 + kq];
        al[mt] = *(const bf16x8*)&Asl[(wm*64 + mt*16 + ln)*72 + kq];
      }
      #pragma unroll
      for (int nt=0;nt<2;nt++){
        bh[nt] = *(const bf16x8*)&Bsh[(wn*32 + nt*16 + ln)*72 + kq];
        bl[nt] = *(const bf16x8*)&Bsl[(wn*32 + nt*16 + ln)*72 + kq];
      }
      #pragma unroll
      for (int mt=0;mt<4;mt++)
        #pragma unroll
        for (int nt=0;nt<2;nt++){
          acc[mt][nt] = __builtin_amdgcn_mfma_f32_16x16x32_bf16(ah[mt], bh[nt], acc[mt][nt], 0,0,0);
          acc[mt][nt] = __builtin_amdgcn_mfma_f32_16x16x32_bf16(ah[mt], bl[nt], acc[mt][nt], 0,0,0);
          acc[mt][nt] = __builtin_amdgcn_mfma_f32_16x16x32_bf16(al[mt], bh[nt], acc[mt][nt], 0,0,0);
        }
    }
    __syncthreads();
  }

  float biasv[2];
  #pragma unroll
  for (int nt=0;nt<2;nt++) biasv[nt] = bias ? bias[n0 + wn*32 + nt*16 + ln] : 0.f;
  #pragma unroll
  for (int mt=0;mt<4;mt++){
    #pragma unroll
    for (int r=0;r<4;r++){
      int row = m0 + wm*64 + mt*16 + quad*4 + r;
      #pragma unroll
      for (int nt=0;nt<2;nt++){
        int col = n0 + wn*32 + nt*16 + ln;
        float v = acc[mt][nt][r] + biasv[nt];
        if (ACT==1) v = fmaxf(v, 0.f);
        if (WF32) C[(size_t)row*N + col] = v;
        if (WSPLIT){
          __hip_bfloat16 h = __float2bfloat16(v);
          Ch[(size_t)row*N + col] = h;
          Cl[(size_t)row*N + col] = __float2bfloat16(v - __bfloat162float(h));
        }
      }
    }
  }
}

// ---------------------------------------------------------------------------
// bf16 MFMA GEMM (post-GRU): BT = B^T [N,K] bf16; 128x128 tile, BK=128.
// RESID: += bf16 resid AFTER act.  SCALE: *= alive.  Write bf16.
// ---------------------------------------------------------------------------
template<int ACT, bool DUAL, bool RESID, bool SCALE>
__global__ __launch_bounds__(256)
void mgemm_k(const __hip_bfloat16* __restrict__ A, const __hip_bfloat16* __restrict__ A2,
             const __hip_bfloat16* __restrict__ BT, const float* __restrict__ bias,
             const unsigned short* __restrict__ resid, const int* __restrict__ dones,
             __hip_bfloat16* __restrict__ Cb, int M, int N, int K)
{
  __shared__ ushort As[128*136];
  __shared__ ushort Bs[128*136];
  const int tid  = threadIdx.x;
  const int lane = tid & 63, wave = tid >> 6;
  const int wm = wave >> 1, wn = wave & 1;
  const int quad = lane >> 4, ln = lane & 15;
  const int n0 = blockIdx.x * 128;
  const int m0 = blockIdx.y * 128;

  f32x4 acc[4][4];
  #pragma unroll
  for (int i=0;i<4;i++)
    #pragma unroll
    for (int j=0;j<4;j++)
      #pragma unroll
      for (int r=0;r<4;r++) acc[i][j][r] = 0.f;

  for (int kc=0; kc<K; kc+=128){
    const __hip_bfloat16* Ab; int arow, akoff;
    if (DUAL) { Ab = kc ? A2 : A; arow = 128; akoff = 0; }
    else      { Ab = A;           arow = K;   akoff = kc; }
    #pragma unroll
    for (int i=0;i<8;i++){
      int c8 = tid + i*256;
      int m = c8 >> 4, kq = (c8 & 15)*8;
      *(uint4*)&As[m*136 + kq] = *(const uint4*)&Ab[(size_t)(m0+m)*arow + akoff + kq];
    }
    #pragma unroll
    for (int i=0;i<8;i++){
      int c8 = tid + i*256;
      int n = c8 >> 4, kq = (c8 & 15)*8;
      *(uint4*)&Bs[n*136 + kq] = *(const uint4*)&BT[(size_t)(n0+n)*K + kc + kq];
    }
    __syncthreads();
    #pragma unroll
    for (int ks=0; ks<4; ks++){
      const int kq = ks*32 + quad*8;
      bf16x8 af[4], bfv[4];
      #pragma unroll
      for (int mt=0;mt<4;mt++)
        af[mt] = *(const bf16x8*)&As[(wm*64 + mt*16 + ln)*136 + kq];
      #pragma unroll
      for (int nt=0;nt<4;nt++)
        bfv[nt] = *(const bf16x8*)&Bs[(wn*64 + nt*16 + ln)*136 + kq];
      #pragma unroll
      for (int mt=0;mt<4;mt++)
        #pragma unroll
        for (int nt=0;nt<4;nt++)
          acc[mt][nt] = __builtin_amdgcn_mfma_f32_16x16x32_bf16(af[mt], bfv[nt], acc[mt][nt], 0,0,0);
    }
    __syncthreads();
  }

  float biasv[4];
  #pragma unroll
  for (int nt=0;nt<4;nt++){
    int col = n0 + wn*64 + nt*16 + ln;
    biasv[nt] = bias ? bias[col] : 0.f;
  }
  #pragma unroll
  for (int mt=0;mt<4;mt++){
    #pragma unroll
    for (int r=0;r<4;r++){
      int row = m0 + wm*64 + mt*16 + quad*4 + r;
      float al = 1.f;
      if (SCALE) al = (dones[row]!=0) ? 0.f : 1.f;
      #pragma unroll
      for (int nt=0;nt<4;nt++){
        int col = n0 + wn*64 + nt*16 + ln;
        float v = acc[mt][nt][r] + biasv[nt];
        if (ACT==1) v = fmaxf(v, 0.f);
        if (RESID)  v += bu2f(resid[(size_t)row*N + col]);
        if (SCALE)  v *= al;
        Cb[(size_t)row*N + col] = __float2bfloat16(v);
      }
    }
  }
}

// ---------------------------------------------------------------------------
// MFMA GRU v4: 128 blocks x 4 rows (vs 32x16 in round 7 — gi stream was
// per-CU-BW-bound at 32 CUs / 256 GB/s). Per-wave MFMA/step unchanged
// (wave owns 48 gate-cols); M=16 is 25% utilized — acceptable.
// Wh hi+lo B-fragments in registers (96 VGPR), staged via LDS.
// gh = h_hi@W_hi + h_lo@W_hi + h_hi@W_lo  (fp32-class).
// gi prefetched one step ahead into registers (3 floats/thread).
// Gate exchange: ghs2[row][392] — stride-1 conflict-free both phases.
// Carry takes the RESET h (round-6 fix); hout gets unreset final h (dnext=0).
// ---------------------------------------------------------------------------
__global__ __launch_bounds__(512, 1)
void grum4_k(const float* __restrict__ giA, const float* __restrict__ giB,
             const float* __restrict__ hidden0,
             const int* __restrict__ dones, const float* __restrict__ gWh,
             const float* __restrict__ bhn, __hip_bfloat16* __restrict__ eb_out,
             float* __restrict__ hout)
{
  __shared__ ushort wstg[32*392];     // weight staging (25 KB)
  __shared__ float  ghs2[4*392];      // [row][gatecol] exchange
  __shared__ ushort hhi[16*136], hlo[16*136];
  __shared__ float  dnS[T_*4];        // [t][row]
  const int tid  = threadIdx.x;
  const int lane = tid & 63, wave = tid >> 6;   // 8 waves
  const int quad = lane >> 4, ln = lane & 15;
  const int r0   = blockIdx.x * 4;
  const int grow = tid >> 7;          // gate row 0..3
  const int gcol = tid & 127;         // gate h-col 0..127

  // dones: tid = t*4+row exactly covers T_*4
  dnS[tid] = (dones[(size_t)(tid>>2)*B_ + r0 + (tid&3)] != 0) ? 1.f : 0.f;
  const float bhnr = bhn[gcol];

  // zero hhi/hlo (rows 4..15 stay zero; rows 0..3 rewritten each step)
  for (int i=tid; i<16*136; i+=512){ hhi[i]=0; hlo[i]=0; }

  // Wh -> hi and lo B-fragments in registers, staged through LDS
  bf16x8 bfh[3][4], bfl[3][4];
  #pragma unroll
  for (int kc=0; kc<4; kc++){    // hi pass
    for (int i=tid; i<32*384; i+=512){
      int kk = i/384, col = i - kk*384;
      wstg[kk*392 + col] = f2bu(gWh[(size_t)(kc*32+kk)*384 + col]);
    }
    __syncthreads();
    #pragma unroll
    for (int ct=0; ct<3; ct++){
      int col = wave*48 + ct*16 + ln;
      #pragma unroll
      for (int j=0;j<8;j++)
        bfh[ct][kc][j] = (short)wstg[(quad*8+j)*392 + col];
    }
    __syncthreads();
  }
  #pragma unroll
  for (int kc=0; kc<4; kc++){    // lo pass
    for (int i=tid; i<32*384; i+=512){
      int kk = i/384, col = i - kk*384;
      float v = gWh[(size_t)(kc*32+kk)*384 + col];
      wstg[kk*392 + col] = f2bu(v - bu2f(f2bu(v)));
    }
    __syncthreads();
    #pragma unroll
    for (int ct=0; ct<3; ct++){
      int col = wave*48 + ct*16 + ln;
      #pragma unroll
      for (int j=0;j<8;j++)
        bfl[ct][kc][j] = (short)wstg[(quad*8+j)*392 + col];
    }
    __syncthreads();
  }

  // init h (apply dones[0])
  float hc = hidden0[(size_t)(r0+grow)*D_ + gcol];
  if (dnS[grow] > 0.5f) hc = 0.f;
  {
    ushort hh = f2bu(hc), hl = f2bu(hc - bu2f(hh));
    hhi[grow*136 + gcol] = hh;
    hlo[grow*136 + gcol] = hl;
  }
  __syncthreads();

  // prime gi for t=0
  float g_r, g_z, g_n;
  {
    const float* gp = giA + ((size_t)(r0 + grow))*384;
    g_r = gp[gcol]; g_z = gp[gcol+128]; g_n = gp[gcol+256];
  }

  for (int t=0; t<T_; t++){
    // prefetch gi for t+1 (hidden behind MFMA phase + barriers)
    float n_r=0.f, n_z=0.f, n_n=0.f;
    if (t+1 < T_){
      const float* gp = (t+1 < 64) ? giA + ((size_t)(t+1)*B_ + r0+grow)*384
                                   : giB + ((size_t)(t+1-64)*B_ + r0+grow)*384;
      n_r = gp[gcol]; n_z = gp[gcol+128]; n_n = gp[gcol+256];
    }

    // MFMA phase: gh[4][384] = h[4][128] @ Wh
    f32x4 acc[3];
    #pragma unroll
    for (int ct=0;ct<3;ct++)
      #pragma unroll
      for (int r=0;r<4;r++) acc[ct][r]=0.f;
    #pragma unroll
    for (int ks=0; ks<4; ks++){
      bf16x8 ahi = *(const bf16x8*)&hhi[ln*136 + ks*32 + quad*8];
      bf16x8 alo = *(const bf16x8*)&hlo[ln*136 + ks*32 + quad*8];
      #pragma unroll
      for (int ct=0;ct<3;ct++){
        acc[ct] = __builtin_amdgcn_mfma_f32_16x16x32_bf16(ahi, bfh[ct][ks], acc[ct], 0,0,0);
        acc[ct] = __builtin_amdgcn_mfma_f32_16x16x32_bf16(alo, bfh[ct][ks], acc[ct], 0,0,0);
        acc[ct] = __builtin_amdgcn_mfma_f32_16x16x32_bf16(ahi, bfl[ct][ks], acc[ct], 0,0,0);
      }
    }
    if (quad == 0){     // C rows 0..3 live in quad 0
      #pragma unroll
      for (int ct=0;ct<3;ct++){
        int col = wave*48 + ct*16 + ln;
        #pragma unroll
        for (int r=0;r<4;r++) ghs2[r*392 + col] = acc[ct][r];
      }
    }
    __syncthreads();

    // gate phase: thread handles (grow, gcol)
    float hr = ghs2[grow*392 + gcol];
    float hz = ghs2[grow*392 + gcol + 128];
    float hn = ghs2[grow*392 + gcol + 256];
    const float dnow  = dnS[t*4 + grow];
    const float dnext = (t+1 < T_) ? dnS[(t+1)*4 + grow] : 0.f;
    float rg = sigmoidf_(g_r + hr);
    float zg = sigmoidf_(g_z + hz);
    float x  = g_n + rg*(hn + bhnr);
    float ng = 2.f/(1.f+__expf(-2.f*x)) - 1.f;   // tanh
    float hnew = (1.f - zg)*ng + zg*hc;
    ((ushort*)eb_out)[((size_t)t*B_ + r0+grow)*D_ + gcol] = f2bu(hnew*(1.f-dnow));
    float hv = (dnext > 0.5f) ? 0.f : hnew;
    hc = hv;                               // carry the RESET h
    ushort hh = f2bu(hv), hl = f2bu(hv - bu2f(hh));
    hhi[grow*136 + gcol] = hh;
    hlo[grow*136 + gcol] = hl;
    __syncthreads();
    g_r = n_r; g_z = n_z; g_n = n_n;
  }
  hout[(size_t)(r0+grow)*D_ + gcol] = hc;
}

// ---------------------------------------------------------------------------
// Coupling per (t,env), bf16 inputs: C_ij = sigmoid(relu(ai+aj+cb).w + cob),
// C_ii=0; ctx[i] = sum_j C_ij e[j] -> bf16.
// ---------------------------------------------------------------------------
__global__ __launch_bounds__(256)
void couple_k(const __hip_bfloat16* __restrict__ acat, const __hip_bfloat16* __restrict__ e,
              const float* __restrict__ chb, const float* __restrict__ cow,
              const float* __restrict__ cob, __hip_bfloat16* __restrict__ ctxb)
{
  __shared__ float ai[NA_][CH_], aj[NA_][CH_], es[NA_][D_], cbw[CH_], cww[CH_], Cs[NA_][NA_];
  const int m0 = blockIdx.x * NA_;
  const int tid = threadIdx.x;

  {
    int j = tid >> 5, q = (tid & 31)*8;
    uint4 u = *(const uint4*)((const ushort*)acat + (size_t)(m0+j)*256 + q);
    float f[8] = {ulo(u.x),uhi(u.x),ulo(u.y),uhi(u.y),ulo(u.z),uhi(u.z),ulo(u.w),uhi(u.w)};
    float* dst = (q < 128) ? &ai[j][q] : &aj[j][q-128];
    #pragma unroll
    for (int i=0;i<8;i++) dst[i] = f[i];
  }
  if (tid < 128){
    int j = tid >> 4, q = (tid & 15)*8;
    uint4 u = *(const uint4*)((const ushort*)e + (size_t)(m0+j)*D_ + q);
    float f[8] = {ulo(u.x),uhi(u.x),ulo(u.y),uhi(u.y),ulo(u.z),uhi(u.z),ulo(u.w),uhi(u.w)};
    #pragma unroll
    for (int i=0;i<8;i++) es[j][q+i] = f[i];
    cbw[tid] = chb[tid]; cww[tid] = cow[tid];
  }
  __syncthreads();

  {
    int p = tid >> 2, q = tid & 3;
    int i = p >> 3, j = p & 7;
    float s = 0.f;
    #pragma unroll
    for (int h = 0; h < 32; h++){
      int hh = q*32 + h;
      s += fmaxf(ai[i][hh] + aj[j][hh] + cbw[hh], 0.f) * cww[hh];
    }
    s += __shfl_down(s, 2);
    s += __shfl_down(s, 1);
    if (q == 0) {
      float Cv = sigmoidf_(s + cob[0]);
      Cs[i][j] = (i==j) ? 0.f : Cv;
    }
  }
  __syncthreads();
  #pragma unroll
  for (int rep=0; rep<4; rep++){
    int idx = rep*256 + tid;
    int i = idx >> 7, d = idx & 127;
    float s = 0.f;
    #pragma unroll
    for (int j=0;j<NA_;j++) s = fmaf(Cs[i][j], es[j][d], s);
    ctxb[(size_t)(m0+i)*D_ + d] = __float2bfloat16(s);
  }
}

__global__ __launch_bounds__(256)
void bcatT_k(const float* __restrict__ chw, __hip_bfloat16* __restrict__ dst)
{
  int idx = blockIdx.x*256 + threadIdx.x;
  int n = idx >> 7, k = idx & 127;
  float v = (n < 128) ? chw[k*128 + n] : chw[(128+k)*128 + (n-128)];
  dst[idx] = __float2bfloat16(v);
}

__global__ __launch_bounds__(256)
void packT_k(const float* __restrict__ src, __hip_bfloat16* __restrict__ dst,
             int R, int Cshift)
{
  int idx = blockIdx.x*256 + threadIdx.x;
  int r = idx >> Cshift, c = idx & ((1<<Cshift)-1);
  dst[c*R + r] = __float2bfloat16(src[idx]);
}

__global__ __launch_bounds__(256)
void packTsplit_k(const float* __restrict__ src, __hip_bfloat16* __restrict__ dh,
                  __hip_bfloat16* __restrict__ dl, int Ccols, int Kshift, int total)
{
  int idx = blockIdx.x*256 + threadIdx.x;
  if (idx >= total) return;
  int n = idx >> Kshift, k = idx & ((1<<Kshift)-1);
  float v = src[k*Ccols + n];
  __hip_bfloat16 h = __float2bfloat16(v);
  dh[idx] = h;
  dl[idx] = __float2bfloat16(v - __bfloat162float(h));
}

__global__ __launch_bounds__(256)
void split_k(const float* __restrict__ src, __hip_bfloat16* __restrict__ dh,
             __hip_bfloat16* __restrict__ dl, int n)
{
  int idx = blockIdx.x*256 + threadIdx.x;
  if (idx >= n) return;
  float v = src[idx];
  __hip_bfloat16 h = __float2bfloat16(v);
  dh[idx] = h;
  dl[idx] = __float2bfloat16(v - __bfloat162float(h));
}

__global__ __launch_bounds__(256)
void vout_k(const __hip_bfloat16* __restrict__ v2, const float* __restrict__ w,
            const float* __restrict__ b, float* __restrict__ values)
{
  int row  = blockIdx.x*4 + (threadIdx.x >> 6);
  int lane = threadIdx.x & 63;
  const ushort* vr = (const ushort*)v2 + (size_t)row*VH_;
  float s = 0.f;
  #pragma unroll
  for (int i=0;i<4;i++) s = fmaf(bu2f(vr[lane + 64*i]), w[lane + 64*i], s);
  #pragma unroll
  for (int off=32; off; off>>=1) s += __shfl_down(s, off);
  if (lane==0) values[row] = s + b[0];
}

extern "C" void kernel_launch(void* const* d_in, const int* in_sizes, int n_in,
                              void* d_out, int out_size, void* d_ws, size_t ws_size,
                              hipStream_t stream) {
  const float* hidden = (const float*)d_in[0];
  const float* obs    = (const float*)d_in[1];
  const int*   dones  = (const int*)  d_in[2];
  const float* e1w = (const float*)d_in[3];
  const float* e1b = (const float*)d_in[4];
  const float* e2w = (const float*)d_in[5];
  const float* e2b = (const float*)d_in[6];
  const float* gWi = (const float*)d_in[7];
  const float* gbi = (const float*)d_in[8];
  const float* gWh = (const float*)d_in[9];
  const float* gbhn= (const float*)d_in[10];
  const float* chw = (const float*)d_in[11];
  const float* chb = (const float*)d_in[12];
  const float* cow = (const float*)d_in[13];
  const float* cob = (const float*)d_in[14];
  const float* uhw = (const float*)d_in[15];
  const float* uhb = (const float*)d_in[16];
  const float* uow = (const float*)d_in[17];
  const float* uob = (const float*)d_in[18];
  const float* v1w = (const float*)d_in[19];
  const float* v1b = (const float*)d_in[20];
  const float* v2w = (const float*)d_in[21];
  const float* v2b = (const float*)d_in[22];
  const float* vow = (const float*)d_in[23];
  const float* vob = (const float*)d_in[24];
  (void)in_sizes; (void)n_in; (void)out_size;

  float* out_hidden = (float*)d_out;
  float* out_values = (float*)d_out + (size_t)B_*D_;

  // Arena (float-slot offsets). Peak 38.1M slots = 152 MB (ws >= 218 MB known).
  float* ws = (float*)d_ws;
  __hip_bfloat16* obsh  = (__hip_bfloat16*)(ws);             // [0, 2.10M)
  __hip_bfloat16* obsl  = (__hip_bfloat16*)(ws + 2097152);   // [2.10M, 4.19M)
  __hip_bfloat16* emb1h = (__hip_bfloat16*)(ws + 4194304);   // [4.19M, 8.39M)
  __hip_bfloat16* emb1l = (__hip_bfloat16*)(ws + 8388608);   // [8.39M, 12.58M)
  __hip_bfloat16* emb2h = (__hip_bfloat16*)(ws + 12582912);  // [12.58M, 16.78M)
  __hip_bfloat16* emb2l = (__hip_bfloat16*)(ws + 16777216);  // [16.78M, 20.97M)
  float* giA = ws;                                            // [0, 12.58M)  overlays obs+emb1
  float* giB = ws + 20971520;                                 // [20.97M, 33.55M)
  __hip_bfloat16* Xe    = (__hip_bfloat16*)(ws + 33554432);   // [33.55M, 37.75M) e bf16
  __hip_bfloat16* wb    = (__hip_bfloat16*)(ws + 37748736);   // weights (~332K slots-as-bf16)
  // post-GRU overlays (gi / emb regions dead):
  __hip_bfloat16* acatB = (__hip_bfloat16*)(ws);              // [0, 8.39M)
  __hip_bfloat16* Xc    = (__hip_bfloat16*)(ws + 8388608);    // [8.39M, 12.58M)
  __hip_bfloat16* Xd    = (__hip_bfloat16*)(ws + 12582912);   // [12.58M, 16.78M)
  __hip_bfloat16* v1b16 = (__hip_bfloat16*)(ws + 20971520);   // [20.97M, 29.36M)
  __hip_bfloat16* v2b16 = (__hip_bfloat16*)(ws);              // [0, 8.39M)  (acat dead)
  if (ws_size < (size_t)38100000 * sizeof(float)) return;

  __hip_bfloat16* bcatT = wb;             // [256][128]
  __hip_bfloat16* uhwT  = wb + 32768;     // [128][256]
  __hip_bfloat16* uowT  = wb + 65536;     // [128][128]
  __hip_bfloat16* v1wT  = wb + 81920;     // [256][128]
  __hip_bfloat16* v2wT  = wb + 114688;    // [256][256]
  __hip_bfloat16* e1wTh = wb + 180224;    // [128][64]
  __hip_bfloat16* e1wTl = wb + 188416;
  __hip_bfloat16* e2wTh = wb + 196608;    // [128][128]
  __hip_bfloat16* e2wTl = wb + 212992;
  __hip_bfloat16* gWiTh = wb + 229376;    // [384][128]
  __hip_bfloat16* gWiTl = wb + 278528;

  dim3 blk(256);
  split_k<<<dim3(16384), blk, 0, stream>>>(obs, obsh, obsl, M_*OBS_);
  packTsplit_k<<<dim3(32),  blk, 0, stream>>>(e1w, e1wTh, e1wTl, 128, 6, 8192);
  packTsplit_k<<<dim3(64),  blk, 0, stream>>>(e2w, e2wTh, e2wTl, 128, 7, 16384);
  packTsplit_k<<<dim3(192), blk, 0, stream>>>(gWi, gWiTh, gWiTl, 384, 7, 49152);
  bcatT_k<<<dim3(128), blk, 0, stream>>>(chw, bcatT);
  packT_k<<<dim3(128), blk, 0, stream>>>(uhw, uhwT, 256, 7);
  packT_k<<<dim3(64),  blk, 0, stream>>>(uow, uowT, 128, 7);
  packT_k<<<dim3(128), blk, 0, stream>>>(v1w, v1wT, 128, 8);
  packT_k<<<dim3(256), blk, 0, stream>>>(v2w, v2wT, 256, 8);

  // embeds (split-precision, fp32-class)
  mgemm3_k<1,false,true><<<dim3(2,512), blk, 0, stream>>>(
    obsh, obsl, e1wTh, e1wTl, e1b, nullptr, emb1h, emb1l, M_, 128, 64);
  mgemm3_k<1,false,true><<<dim3(2,512), blk, 0, stream>>>(
    emb1h, emb1l, e2wTh, e2wTl, e2b, nullptr, emb2h, emb2l, M_, 128, 128);
  // gi in two halves (fp32 out): t=0..63 -> giA (overlays dead obs/emb1), t=64..127 -> giB
  mgemm3_k<0,true,false><<<dim3(6,256), blk, 0, stream>>>(
    emb2h, emb2l, gWiTh, gWiTl, gbi, giA, nullptr, nullptr, M_/2, 384, 128);
  mgemm3_k<0,true,false><<<dim3(6,256), blk, 0, stream>>>(
    emb2h + (size_t)(M_/2)*D_, emb2l + (size_t)(M_/2)*D_, gWiTh, gWiTl, gbi, giB,
    nullptr, nullptr, M_/2, 384, 128);

  // MFMA GRU: one dispatch, 128 blocks x 4 rows
  grum4_k<<<dim3(128), dim3(512), 0, stream>>>(giA, giB, hidden, dones, gWh, gbhn, Xe, out_hidden);

  for (int it=0; it<2; it++){
    mgemm_k<0,false,false,false><<<dim3(2,512), blk, 0, stream>>>(
      Xe, nullptr, bcatT, nullptr, nullptr, nullptr, acatB, M_, 256, 128);
    couple_k<<<dim3(T_*NE_), blk, 0, stream>>>(acatB, Xe, chb, cow, cob, Xc);
    mgemm_k<1,true,false,false><<<dim3(1,512), blk, 0, stream>>>(
      Xe, Xc, uhwT, uhb, nullptr, nullptr, Xd, M_, 128, 256);
    mgemm_k<1,false,true,true><<<dim3(1,512), blk, 0, stream>>>(
      Xd, nullptr, uowT, uob, (const unsigned short*)Xe, dones, Xe, M_, 128, 128);
  }
  mgemm_k<1,false,false,false><<<dim3(2,512), blk, 0, stream>>>(
    Xe, nullptr, v1wT, v1b, nullptr, nullptr, v1b16, M_, 256, 128);
  mgemm_k<1,false,false,false><<<dim3(2,512), blk, 0, stream>>>(
    v1b16, nullptr, v2wT, v2b, nullptr, nullptr, v2b16, M_, 256, 256);
  vout_k<<<dim3(M_/4), blk, 0, stream>>>(v2b16, vow, vob, out_values);
}